// Round 1
// baseline (987.680 us; speedup 1.0000x reference)
//
#include <hip/hip_runtime.h>
#include <math.h>

#define B 16
#define N 2048
#define M 2048
#define BN (B * N)
#define LOG2E 1.4426950408889634f

#define CJ 512          // columns (or rows) per LDS chunk
#define NCHUNK (M / CJ) // 4
#define RB 256          // rows (or cols) per workgroup = blockDim.x

#if __has_builtin(__builtin_amdgcn_exp2f)
#define EXP2F(x) __builtin_amdgcn_exp2f(x)
#else
#define EXP2F(x) exp2f(x)
#endif

#if __has_builtin(__builtin_amdgcn_sqrtf)
#define SQRTF(x) __builtin_amdgcn_sqrtf(x)
#else
#define SQRTF(x) sqrtf(x)
#endif

// ---------------------------------------------------------------------------
// init: remainl/remainr = 1 (n==m so both factors are 1), accumulators = 0,
// cost = 0. d_out and d_ws are poisoned before every call, so this runs every
// launch.
// ---------------------------------------------------------------------------
__global__ __launch_bounds__(256) void k_init(float* __restrict__ rl,
                                              float* __restrict__ rr,
                                              float* __restrict__ rowsum,
                                              float* __restrict__ ss2,
                                              float* __restrict__ t1acc,
                                              float* __restrict__ cost) {
    int idx = blockIdx.x * 256 + threadIdx.x;
    if (idx < BN) {
        rl[idx] = 1.0f;
        rr[idx] = 1.0f;
        rowsum[idx] = 0.0f;
        ss2[idx] = 0.0f;
        t1acc[idx] = 0.0f;
    }
    if (idx < B) cost[idx] = 0.0f;
}

// ---------------------------------------------------------------------------
// Pass 1: rowsum[b][i] = sum_j exp2(c2*d2(i,j)) * rr[j]
// Grid: (NCHUNK, N/RB, B); each thread owns one row, sweeps a CJ-column chunk
// staged in LDS as {x2,y2,z2,rr}.
// ---------------------------------------------------------------------------
__global__ __launch_bounds__(256) void k_rowsum(const float* __restrict__ xyz1,
                                                const float* __restrict__ xyz2,
                                                const float* __restrict__ rr,
                                                float* __restrict__ rowsum,
                                                float c2) {
    __shared__ float4 tile[CJ];
    const int b = blockIdx.z;
    const int i = blockIdx.y * RB + threadIdx.x;
    const int j0 = blockIdx.x * CJ;

    for (int t = threadIdx.x; t < CJ; t += 256) {
        int j = j0 + t;
        const float* p = xyz2 + ((size_t)b * M + j) * 3;
        tile[t] = make_float4(p[0], p[1], p[2], rr[b * M + j]);
    }
    __syncthreads();

    const float* p1 = xyz1 + ((size_t)b * N + i) * 3;
    const float x1 = p1[0], y1 = p1[1], z1 = p1[2];
    float acc = 0.0f;
#pragma unroll 8
    for (int t = 0; t < CJ; ++t) {
        float4 p = tile[t];
        float dx = x1 - p.x, dy = y1 - p.y, dz = z1 - p.z;
        float d2 = fmaf(dx, dx, fmaf(dy, dy, dz * dz));
        acc = fmaf(EXP2F(c2 * d2), p.w, acc);
    }
    atomicAdd(&rowsum[b * N + i], acc);
}

// ---------------------------------------------------------------------------
// Pass 2: ss2[b][j] = rr[j] * sum_i exp2(c2*d2(i,j)) * a[i],
//         a[i] = rl[i] / (rowsum[i] + 1e-9)
// Same tiling, transposed: thread owns a column, LDS holds {x1,y1,z1,a}.
// ---------------------------------------------------------------------------
__global__ __launch_bounds__(256) void k_colsum(const float* __restrict__ xyz1,
                                                const float* __restrict__ xyz2,
                                                const float* __restrict__ rl,
                                                const float* __restrict__ rowsum,
                                                const float* __restrict__ rr,
                                                float* __restrict__ ss2,
                                                float c2) {
    __shared__ float4 tile[CJ];
    const int b = blockIdx.z;
    const int j = blockIdx.y * RB + threadIdx.x;
    const int i0 = blockIdx.x * CJ;

    for (int t = threadIdx.x; t < CJ; t += 256) {
        int i = i0 + t;
        const float* p = xyz1 + ((size_t)b * N + i) * 3;
        float a = rl[b * N + i] / (rowsum[b * N + i] + 1e-9f);
        tile[t] = make_float4(p[0], p[1], p[2], a);
    }
    __syncthreads();

    const float* p2 = xyz2 + ((size_t)b * M + j) * 3;
    const float x2 = p2[0], y2 = p2[1], z2 = p2[2];
    float acc = 0.0f;
#pragma unroll 8
    for (int t = 0; t < CJ; ++t) {
        float4 p = tile[t];
        float dx = p.x - x2, dy = p.y - y2, dz = p.z - z2;
        float d2 = fmaf(dx, dx, fmaf(dy, dy, dz * dz));
        acc = fmaf(EXP2F(c2 * d2), p.w, acc);
    }
    atomicAdd(&ss2[b * M + j], acc * rr[b * M + j]);
}

// ---------------------------------------------------------------------------
// Tiny per-column update: s = min(rr/(ss2+1e-9),1); q = rr*s; rr -= ss2*s
// ---------------------------------------------------------------------------
__global__ __launch_bounds__(256) void k_update(float* __restrict__ rr,
                                                const float* __restrict__ ss2,
                                                float* __restrict__ q) {
    int idx = blockIdx.x * 256 + threadIdx.x;
    float rrv = rr[idx];
    float sv = ss2[idx];
    float s = fminf(rrv / (sv + 1e-9f), 1.0f);
    q[idx] = rrv * s;
    rr[idx] = fmaxf(rrv - sv * s, 0.0f);
}

// ---------------------------------------------------------------------------
// Pass 3: per row i: T1 = sum_j e*q[j]; T2 = sum_j e*q[j]*dist(i,j)
//   t1acc[i] += T1 (atomic across column chunks)
//   cost[b]  += a[i]*T2 (wave-reduced, then atomic)
// ---------------------------------------------------------------------------
__global__ __launch_bounds__(256) void k_finrow(const float* __restrict__ xyz1,
                                                const float* __restrict__ xyz2,
                                                const float* __restrict__ q,
                                                const float* __restrict__ rl,
                                                const float* __restrict__ rowsum,
                                                float* __restrict__ t1acc,
                                                float* __restrict__ cost,
                                                float c2) {
    __shared__ float4 tile[CJ];
    const int b = blockIdx.z;
    const int i = blockIdx.y * RB + threadIdx.x;
    const int j0 = blockIdx.x * CJ;

    for (int t = threadIdx.x; t < CJ; t += 256) {
        int j = j0 + t;
        const float* p = xyz2 + ((size_t)b * M + j) * 3;
        tile[t] = make_float4(p[0], p[1], p[2], q[b * M + j]);
    }
    __syncthreads();

    const float* p1 = xyz1 + ((size_t)b * N + i) * 3;
    const float x1 = p1[0], y1 = p1[1], z1 = p1[2];
    float T1 = 0.0f, T2 = 0.0f;
#pragma unroll 8
    for (int t = 0; t < CJ; ++t) {
        float4 p = tile[t];
        float dx = x1 - p.x, dy = y1 - p.y, dz = z1 - p.z;
        float d2 = fmaf(dx, dx, fmaf(dy, dy, dz * dz));
        float wq = EXP2F(c2 * d2) * p.w;
        T1 += wq;
        T2 = fmaf(wq, SQRTF(fmaxf(d2, 1e-12f)), T2);
    }
    atomicAdd(&t1acc[b * N + i], T1);

    float a = rl[b * N + i] / (rowsum[b * N + i] + 1e-9f);
    float contrib = a * T2;
#pragma unroll
    for (int off = 32; off > 0; off >>= 1)
        contrib += __shfl_down(contrib, off, 64);
    if ((threadIdx.x & 63) == 0) atomicAdd(&cost[b], contrib);
}

// ---------------------------------------------------------------------------
// Per-row finalize: rl = max(rl - a*T1, 0); zero accumulators for next level.
// (rowsum/ss2/t1acc are fully consumed by this point in the level.)
// ---------------------------------------------------------------------------
__global__ __launch_bounds__(256) void k_finalize(float* __restrict__ rl,
                                                  float* __restrict__ rowsum,
                                                  float* __restrict__ ss2,
                                                  float* __restrict__ t1acc) {
    int idx = blockIdx.x * 256 + threadIdx.x;
    float a = rl[idx] / (rowsum[idx] + 1e-9f);
    rl[idx] = fmaxf(rl[idx] - a * t1acc[idx], 0.0f);
    rowsum[idx] = 0.0f;
    ss2[idx] = 0.0f;
    t1acc[idx] = 0.0f;
}

extern "C" void kernel_launch(void* const* d_in, const int* in_sizes, int n_in,
                              void* d_out, int out_size, void* d_ws, size_t ws_size,
                              hipStream_t stream) {
    const float* xyz1 = (const float*)d_in[0];
    const float* xyz2 = (const float*)d_in[1];
    float* cost = (float*)d_out;

    float* ws = (float*)d_ws;
    float* rl = ws + 0 * BN;
    float* rr = ws + 1 * BN;
    float* rowsum = ws + 2 * BN;
    float* ss2 = ws + 3 * BN;
    float* q = ws + 4 * BN;
    float* t1acc = ws + 5 * BN;

    static const float levels[10] = {-16384.0f, -4096.0f, -1024.0f, -256.0f,
                                     -64.0f,    -16.0f,   -4.0f,    -1.0f,
                                     -0.25f,    0.0f};

    k_init<<<dim3(BN / 256), dim3(256), 0, stream>>>(rl, rr, rowsum, ss2, t1acc, cost);

    dim3 grid(NCHUNK, N / RB, B);
    dim3 blk(256);
    dim3 small(BN / 256);

    for (int l = 0; l < 10; ++l) {
        float c2 = levels[l] * LOG2E;
        k_rowsum<<<grid, blk, 0, stream>>>(xyz1, xyz2, rr, rowsum, c2);
        k_colsum<<<grid, blk, 0, stream>>>(xyz1, xyz2, rl, rowsum, rr, ss2, c2);
        k_update<<<small, blk, 0, stream>>>(rr, ss2, q);
        k_finrow<<<grid, blk, 0, stream>>>(xyz1, xyz2, q, rl, rowsum, t1acc, cost, c2);
        k_finalize<<<small, blk, 0, stream>>>(rl, rowsum, ss2, t1acc);
    }
}

// Round 2
// 925.719 us; speedup vs baseline: 1.0669x; 1.0669x over previous
//
#include <hip/hip_runtime.h>
#include <math.h>

#define B 16
#define N 2048
#define M 2048
#define BN (B * N)
#define LOG2E 1.4426950408889634f

#define CJ 256          // elements per LDS chunk
#define NCH (M / CJ)    // 8 chunks -> 1024 WGs per sweep
#define RB 256          // threads per WG

#define EXP2F(x) __builtin_amdgcn_exp2f(x)
#define SQRTF(x) __builtin_amdgcn_sqrtf(x)

// ---------------------------------------------------------------------------
// init: rl=1, rr(buf0)=1, zero both rowsum buffers, ss2, t1acc, cost.
// ws is re-poisoned to 0xAA before every call, so this must run every launch.
// ---------------------------------------------------------------------------
__global__ __launch_bounds__(256) void k_init(float* __restrict__ rl,
                                              float* __restrict__ rr0,
                                              float* __restrict__ rs0,
                                              float* __restrict__ rs1,
                                              float* __restrict__ ss2,
                                              float* __restrict__ t1acc,
                                              float* __restrict__ cost) {
    int idx = blockIdx.x * 256 + threadIdx.x;
    rl[idx] = 1.0f;
    rr0[idx] = 1.0f;
    rs0[idx] = 0.0f;
    rs1[idx] = 0.0f;
    ss2[idx] = 0.0f;
    t1acc[idx] = 0.0f;
    if (idx < B) cost[idx] = 0.0f;
}

// ---------------------------------------------------------------------------
// Initial rowsum for level 0 (rr == 1): rowsum[b][i] = sum_j exp2(c2*d2(i,j))
// Grid: (NCH, N/RB, B)
// ---------------------------------------------------------------------------
__global__ __launch_bounds__(256) void k_rowsum0(const float* __restrict__ xyz1,
                                                 const float* __restrict__ xyz2,
                                                 float* __restrict__ rowsum,
                                                 float c2) {
    __shared__ float4 tile[CJ];
    const int b = blockIdx.z;
    const int i = blockIdx.y * RB + threadIdx.x;
    const int j = blockIdx.x * CJ + threadIdx.x;

    {
        const float* p = xyz2 + ((size_t)b * M + j) * 3;
        tile[threadIdx.x] = make_float4(p[0], p[1], p[2], 0.0f);
    }
    __syncthreads();

    const float* p1 = xyz1 + ((size_t)b * N + i) * 3;
    const float x1 = p1[0], y1 = p1[1], z1 = p1[2];
    float acc = 0.0f;
#pragma unroll 8
    for (int t = 0; t < CJ; ++t) {
        float4 p = tile[t];
        float dx = x1 - p.x, dy = y1 - p.y, dz = z1 - p.z;
        float d2 = fmaf(dx, dx, fmaf(dy, dy, dz * dz));
        acc += EXP2F(c2 * d2);
    }
    atomicAdd(&rowsum[b * N + i], acc);
}

// ---------------------------------------------------------------------------
// Column sweep: ss2[b][j] = rr[j] * sum_i exp2(c2*d2(i,j)) * a[i],
//   a[i] = rl[i]/(rowsum[i]+1e-9). Tiles the i dimension; thread owns col j.
// Grid: (NCH, M/RB, B)
// ---------------------------------------------------------------------------
__global__ __launch_bounds__(256) void k_colsum(const float* __restrict__ xyz1,
                                                const float* __restrict__ xyz2,
                                                const float* __restrict__ rl,
                                                const float* __restrict__ rowsum,
                                                const float* __restrict__ rr,
                                                float* __restrict__ ss2,
                                                float c2) {
    __shared__ float4 tile[CJ];
    const int b = blockIdx.z;
    const int j = blockIdx.y * RB + threadIdx.x;
    const int i = blockIdx.x * CJ + threadIdx.x;

    {
        const float* p = xyz1 + ((size_t)b * N + i) * 3;
        float a = rl[b * N + i] / (rowsum[b * N + i] + 1e-9f);
        tile[threadIdx.x] = make_float4(p[0], p[1], p[2], a);
    }
    __syncthreads();

    const float* p2 = xyz2 + ((size_t)b * M + j) * 3;
    const float x2 = p2[0], y2 = p2[1], z2 = p2[2];
    float acc = 0.0f;
#pragma unroll 8
    for (int t = 0; t < CJ; ++t) {
        float4 p = tile[t];
        float dx = p.x - x2, dy = p.y - y2, dz = p.z - z2;
        float d2 = fmaf(dx, dx, fmaf(dy, dy, dz * dz));
        acc = fmaf(EXP2F(c2 * d2), p.w, acc);
    }
    atomicAdd(&ss2[b * M + j], acc * rr[b * M + j]);
}

// ---------------------------------------------------------------------------
// Fused finrow(l) + rowsum(l+1).
// Tile load (per column j): s = min(rr/(ss2+1e-9),1); q = rr*s;
//   rr_new = max(rr-ss2*s,0)  [written by blockIdx.y==0 into rr_out].
// Inner loop (per row i):
//   MODE 0 (levels 0..7, c2_l = 4*c2_n): en = exp2(c2_n*d2); el = en^4
//   MODE 1 (level 8, next level = 0):    el = exp2(c2_l*d2); en = 1
//   MODE 2 (level 9, no next level):     el = exp2(c2_l*d2); no rs
//   T1 += el*q; T2 += el*q*dist; rs += en*rr_new
// Epilogue: t1acc[i] += T1; rowsum_next[i] += rs; cost[b] += a[i]*T2.
// Grid: (NCH, N/RB, B)
// ---------------------------------------------------------------------------
template <int MODE>
__global__ __launch_bounds__(256) void k_fused(const float* __restrict__ xyz1,
                                               const float* __restrict__ xyz2,
                                               const float* __restrict__ rr_in,
                                               float* __restrict__ rr_out,
                                               const float* __restrict__ ss2,
                                               const float* __restrict__ rl,
                                               const float* __restrict__ rowsum_cur,
                                               float* __restrict__ rowsum_next,
                                               float* __restrict__ t1acc,
                                               float* __restrict__ cost,
                                               float c2l, float c2n) {
    __shared__ float4 tile[CJ];   // x2,y2,z2,q
    __shared__ float rrn_s[CJ];   // rr_new
    const int b = blockIdx.z;
    const int i = blockIdx.y * RB + threadIdx.x;
    const int j = blockIdx.x * CJ + threadIdx.x;

    {
        const float* p = xyz2 + ((size_t)b * M + j) * 3;
        float rrv = rr_in[b * M + j];
        float sv = ss2[b * M + j];
        float s = fminf(rrv / (sv + 1e-9f), 1.0f);
        float qv = rrv * s;
        float rrn = fmaxf(rrv - sv * s, 0.0f);
        tile[threadIdx.x] = make_float4(p[0], p[1], p[2], qv);
        rrn_s[threadIdx.x] = rrn;
        if (MODE != 2 && blockIdx.y == 0) rr_out[b * M + j] = rrn;
    }
    __syncthreads();

    const float* p1 = xyz1 + ((size_t)b * N + i) * 3;
    const float x1 = p1[0], y1 = p1[1], z1 = p1[2];
    float T1 = 0.0f, T2 = 0.0f, rs = 0.0f;
#pragma unroll 8
    for (int t = 0; t < CJ; ++t) {
        float4 p = tile[t];
        float dx = x1 - p.x, dy = y1 - p.y, dz = z1 - p.z;
        float d2 = fmaf(dx, dx, fmaf(dy, dy, dz * dz));
        float el, en;
        if (MODE == 0) {
            en = EXP2F(c2n * d2);
            float e2 = en * en;
            el = e2 * e2;
        } else {
            el = EXP2F(c2l * d2);
            en = 1.0f;
        }
        float wq = el * p.w;
        T1 += wq;
        T2 = fmaf(wq, SQRTF(fmaxf(d2, 1e-12f)), T2);
        if (MODE == 0)
            rs = fmaf(en, rrn_s[t], rs);
        else if (MODE == 1)
            rs += rrn_s[t];
    }
    atomicAdd(&t1acc[b * N + i], T1);
    if (MODE != 2) atomicAdd(&rowsum_next[b * N + i], rs);

    float a = rl[b * N + i] / (rowsum_cur[b * N + i] + 1e-9f);
    float contrib = a * T2;
#pragma unroll
    for (int off = 32; off > 0; off >>= 1)
        contrib += __shfl_down(contrib, off, 64);
    if ((threadIdx.x & 63) == 0) atomicAdd(&cost[b], contrib);
}

// ---------------------------------------------------------------------------
// Per-level epilogue: rl = max(rl - a*t1acc, 0); zero consumed accumulators.
// ---------------------------------------------------------------------------
__global__ __launch_bounds__(256) void k_post(float* __restrict__ rl,
                                              float* __restrict__ rowsum_cur,
                                              float* __restrict__ ss2,
                                              float* __restrict__ t1acc) {
    int idx = blockIdx.x * 256 + threadIdx.x;
    float a = rl[idx] / (rowsum_cur[idx] + 1e-9f);
    rl[idx] = fmaxf(rl[idx] - a * t1acc[idx], 0.0f);
    rowsum_cur[idx] = 0.0f;
    ss2[idx] = 0.0f;
    t1acc[idx] = 0.0f;
}

extern "C" void kernel_launch(void* const* d_in, const int* in_sizes, int n_in,
                              void* d_out, int out_size, void* d_ws, size_t ws_size,
                              hipStream_t stream) {
    const float* xyz1 = (const float*)d_in[0];
    const float* xyz2 = (const float*)d_in[1];
    float* cost = (float*)d_out;

    float* ws = (float*)d_ws;
    float* rl = ws + 0 * BN;
    float* rr[2] = {ws + 1 * BN, ws + 2 * BN};
    float* rs[2] = {ws + 3 * BN, ws + 4 * BN};
    float* ss2 = ws + 5 * BN;
    float* t1acc = ws + 6 * BN;

    static const float levels[10] = {-16384.0f, -4096.0f, -1024.0f, -256.0f,
                                     -64.0f,    -16.0f,   -4.0f,    -1.0f,
                                     -0.25f,    0.0f};
    float c2[10];
    for (int l = 0; l < 10; ++l) c2[l] = levels[l] * LOG2E;

    dim3 grid(NCH, N / RB, B);
    dim3 blk(256);
    dim3 small(BN / 256);

    k_init<<<small, blk, 0, stream>>>(rl, rr[0], rs[0], rs[1], ss2, t1acc, cost);
    k_rowsum0<<<grid, blk, 0, stream>>>(xyz1, xyz2, rs[0], c2[0]);

    for (int l = 0; l < 10; ++l) {
        int p = l & 1;
        k_colsum<<<grid, blk, 0, stream>>>(xyz1, xyz2, rl, rs[p], rr[p], ss2, c2[l]);
        if (l <= 7)
            k_fused<0><<<grid, blk, 0, stream>>>(xyz1, xyz2, rr[p], rr[1 - p], ss2, rl,
                                                 rs[p], rs[1 - p], t1acc, cost,
                                                 c2[l], c2[l + 1]);
        else if (l == 8)
            k_fused<1><<<grid, blk, 0, stream>>>(xyz1, xyz2, rr[p], rr[1 - p], ss2, rl,
                                                 rs[p], rs[1 - p], t1acc, cost,
                                                 c2[l], 0.0f);
        else
            k_fused<2><<<grid, blk, 0, stream>>>(xyz1, xyz2, rr[p], rr[1 - p], ss2, rl,
                                                 rs[p], rs[1 - p], t1acc, cost,
                                                 c2[l], 0.0f);
        if (l < 9)
            k_post<<<small, blk, 0, stream>>>(rl, rs[p], ss2, t1acc);
    }
}

// Round 3
// 920.301 us; speedup vs baseline: 1.0732x; 1.0059x over previous
//
#include <hip/hip_runtime.h>
#include <math.h>

#define B 16
#define N 2048
#define M 2048
#define BN (B * N)
#define LOG2E 1.4426950408889634f

#define CJ 128            // tile elements per LDS chunk
#define NCH (M / CJ)      // 16 chunks
#define TPB 128           // threads per block (2 waves)
#define RPT 2             // rows (or cols) per thread
#define RBLK (TPB * RPT)  // 256 rows per WG
// grid per sweep: NCH x (N/RBLK) x B = 16 x 8 x 16 = 2048 WGs

#define EXP2F(x) __builtin_amdgcn_exp2f(x)
#define SQRTF(x) __builtin_amdgcn_sqrtf(x)

// ---------------------------------------------------------------------------
// init: rl=1, rr(buf0)=1, zero rowsum bufs, ss2, t1acc, cost.
// ws/d_out are re-poisoned before every call, so this runs every launch.
// ---------------------------------------------------------------------------
__global__ __launch_bounds__(256) void k_init(float* __restrict__ rl,
                                              float* __restrict__ rr0,
                                              float* __restrict__ rs0,
                                              float* __restrict__ rs1,
                                              float* __restrict__ ss2,
                                              float* __restrict__ t1acc,
                                              float* __restrict__ cost) {
    int idx = blockIdx.x * 256 + threadIdx.x;
    rl[idx] = 1.0f;
    rr0[idx] = 1.0f;
    rs0[idx] = 0.0f;
    rs1[idx] = 0.0f;
    ss2[idx] = 0.0f;
    t1acc[idx] = 0.0f;
    if (idx < B) cost[idx] = 0.0f;
}

// ---------------------------------------------------------------------------
// Initial rowsum for level 0 (rr == 1): rowsum[i] += sum_j exp2(c2*d2(i,j))
// ---------------------------------------------------------------------------
__global__ __launch_bounds__(TPB) void k_rowsum0(const float* __restrict__ xyz1,
                                                 const float* __restrict__ xyz2,
                                                 float* __restrict__ rowsum,
                                                 float c2) {
    __shared__ float4 tile[CJ];
    const int b = blockIdx.z;
    const int i0 = blockIdx.y * RBLK + threadIdx.x;
    const int i1 = i0 + TPB;

    if (threadIdx.x < CJ) {
        int j = blockIdx.x * CJ + threadIdx.x;
        const float* p = xyz2 + ((size_t)b * M + j) * 3;
        tile[threadIdx.x] = make_float4(p[0], p[1], p[2], 0.0f);
    }
    __syncthreads();

    const float* pa = xyz1 + ((size_t)b * N + i0) * 3;
    const float* pb = xyz1 + ((size_t)b * N + i1) * 3;
    const float xa = pa[0], ya = pa[1], za = pa[2];
    const float xb = pb[0], yb = pb[1], zb = pb[2];
    float acc0 = 0.0f, acc1 = 0.0f;
#pragma unroll 8
    for (int t = 0; t < CJ; ++t) {
        float4 p = tile[t];
        float dxa = xa - p.x, dya = ya - p.y, dza = za - p.z;
        float dxb = xb - p.x, dyb = yb - p.y, dzb = zb - p.z;
        float d2a = fmaf(dxa, dxa, fmaf(dya, dya, dza * dza));
        float d2b = fmaf(dxb, dxb, fmaf(dyb, dyb, dzb * dzb));
        acc0 += EXP2F(c2 * d2a);
        acc1 += EXP2F(c2 * d2b);
    }
    atomicAdd(&rowsum[b * N + i0], acc0);
    atomicAdd(&rowsum[b * N + i1], acc1);
}

// ---------------------------------------------------------------------------
// Column sweep: ss2[j] += rr[j] * sum_i exp2(c2*d2(i,j)) * a[i],
//   a[i] = rl[i]/(rowsum[i]+1e-9). Thread owns 2 cols; LDS tiles the rows.
// ZL: level value is 0 -> exp2 == 1.
// ---------------------------------------------------------------------------
template <bool ZL>
__global__ __launch_bounds__(TPB) void k_colsum(const float* __restrict__ xyz1,
                                                const float* __restrict__ xyz2,
                                                const float* __restrict__ rl,
                                                const float* __restrict__ rowsum,
                                                const float* __restrict__ rr,
                                                float* __restrict__ ss2,
                                                float c2) {
    __shared__ float4 tile[CJ];
    const int b = blockIdx.z;
    const int j0 = blockIdx.y * RBLK + threadIdx.x;
    const int j1 = j0 + TPB;

    if (threadIdx.x < CJ) {
        int i = blockIdx.x * CJ + threadIdx.x;
        const float* p = xyz1 + ((size_t)b * N + i) * 3;
        float a = rl[b * N + i] / (rowsum[b * N + i] + 1e-9f);
        tile[threadIdx.x] = make_float4(p[0], p[1], p[2], a);
    }
    __syncthreads();

    const float* pa = xyz2 + ((size_t)b * M + j0) * 3;
    const float* pb = xyz2 + ((size_t)b * M + j1) * 3;
    const float xa = pa[0], ya = pa[1], za = pa[2];
    const float xb = pb[0], yb = pb[1], zb = pb[2];
    float acc0 = 0.0f, acc1 = 0.0f;
#pragma unroll 8
    for (int t = 0; t < CJ; ++t) {
        float4 p = tile[t];
        if (ZL) {
            acc0 += p.w;
            acc1 += p.w;
        } else {
            float dxa = p.x - xa, dya = p.y - ya, dza = p.z - za;
            float dxb = p.x - xb, dyb = p.y - yb, dzb = p.z - zb;
            float d2a = fmaf(dxa, dxa, fmaf(dya, dya, dza * dza));
            float d2b = fmaf(dxb, dxb, fmaf(dyb, dyb, dzb * dzb));
            acc0 = fmaf(EXP2F(c2 * d2a), p.w, acc0);
            acc1 = fmaf(EXP2F(c2 * d2b), p.w, acc1);
        }
    }
    atomicAdd(&ss2[b * M + j0], acc0 * rr[b * M + j0]);
    atomicAdd(&ss2[b * M + j1], acc1 * rr[b * M + j1]);
}

// ---------------------------------------------------------------------------
// Fused finrow(l) + rowsum(l+1). Thread owns 2 rows; LDS tiles the cols.
// Tile load (col j): s=min(rr/(ss2+1e-9),1); q=rr*s; rrn=max(rr-ss2*s,0).
// MODE 0 (l=0..7): en=exp2(c2n*d2), el=en^4. MODE 1 (l=8): el=exp2(c2l*d2),
// en=1. MODE 2 (l=9, c2l=0): el=1, no rs.
// ---------------------------------------------------------------------------
template <int MODE>
__global__ __launch_bounds__(TPB) void k_fused(const float* __restrict__ xyz1,
                                               const float* __restrict__ xyz2,
                                               const float* __restrict__ rr_in,
                                               float* __restrict__ rr_out,
                                               const float* __restrict__ ss2,
                                               const float* __restrict__ rl,
                                               const float* __restrict__ rowsum_cur,
                                               float* __restrict__ rowsum_next,
                                               float* __restrict__ t1acc,
                                               float* __restrict__ cost,
                                               float c2l, float c2n) {
    __shared__ float4 tile[CJ];  // x2,y2,z2,q
    __shared__ float rrn_s[CJ];  // rr_new
    const int b = blockIdx.z;
    const int i0 = blockIdx.y * RBLK + threadIdx.x;
    const int i1 = i0 + TPB;

    if (threadIdx.x < CJ) {
        int j = blockIdx.x * CJ + threadIdx.x;
        const float* p = xyz2 + ((size_t)b * M + j) * 3;
        float rrv = rr_in[b * M + j];
        float sv = ss2[b * M + j];
        float s = fminf(rrv / (sv + 1e-9f), 1.0f);
        float qv = rrv * s;
        float rrn = fmaxf(rrv - sv * s, 0.0f);
        tile[threadIdx.x] = make_float4(p[0], p[1], p[2], qv);
        rrn_s[threadIdx.x] = rrn;
        if (MODE != 2 && blockIdx.y == 0) rr_out[b * M + j] = rrn;
    }
    __syncthreads();

    const float* pa = xyz1 + ((size_t)b * N + i0) * 3;
    const float* pb = xyz1 + ((size_t)b * N + i1) * 3;
    const float xa = pa[0], ya = pa[1], za = pa[2];
    const float xb = pb[0], yb = pb[1], zb = pb[2];
    float T1a = 0.0f, T2a = 0.0f, rsa = 0.0f;
    float T1b = 0.0f, T2b = 0.0f, rsb = 0.0f;
#pragma unroll 8
    for (int t = 0; t < CJ; ++t) {
        float4 p = tile[t];
        float dxa = xa - p.x, dya = ya - p.y, dza = za - p.z;
        float dxb = xb - p.x, dyb = yb - p.y, dzb = zb - p.z;
        float d2a = fmaf(dxa, dxa, fmaf(dya, dya, dza * dza));
        float d2b = fmaf(dxb, dxb, fmaf(dyb, dyb, dzb * dzb));
        float ela, elb, ena, enb;
        if (MODE == 0) {
            ena = EXP2F(c2n * d2a);
            enb = EXP2F(c2n * d2b);
            float e2a = ena * ena, e2b = enb * enb;
            ela = e2a * e2a;
            elb = e2b * e2b;
        } else if (MODE == 1) {
            ela = EXP2F(c2l * d2a);
            elb = EXP2F(c2l * d2b);
            ena = enb = 1.0f;
        } else {
            ela = elb = 1.0f;
            ena = enb = 1.0f;
        }
        float wqa = ela * p.w;
        float wqb = elb * p.w;
        T1a += wqa;
        T1b += wqb;
        T2a = fmaf(wqa, SQRTF(fmaxf(d2a, 1e-12f)), T2a);
        T2b = fmaf(wqb, SQRTF(fmaxf(d2b, 1e-12f)), T2b);
        if (MODE == 0) {
            float rrn = rrn_s[t];
            rsa = fmaf(ena, rrn, rsa);
            rsb = fmaf(enb, rrn, rsb);
        } else if (MODE == 1) {
            float rrn = rrn_s[t];
            rsa += rrn;
            rsb += rrn;
        }
    }
    atomicAdd(&t1acc[b * N + i0], T1a);
    atomicAdd(&t1acc[b * N + i1], T1b);
    if (MODE != 2) {
        atomicAdd(&rowsum_next[b * N + i0], rsa);
        atomicAdd(&rowsum_next[b * N + i1], rsb);
    }

    float aa = rl[b * N + i0] / (rowsum_cur[b * N + i0] + 1e-9f);
    float ab = rl[b * N + i1] / (rowsum_cur[b * N + i1] + 1e-9f);
    float contrib = fmaf(aa, T2a, ab * T2b);
#pragma unroll
    for (int off = 32; off > 0; off >>= 1)
        contrib += __shfl_down(contrib, off, 64);
    if ((threadIdx.x & 63) == 0) atomicAdd(&cost[b], contrib);
}

// ---------------------------------------------------------------------------
// Per-level epilogue: rl = max(rl - a*t1acc, 0); zero consumed accumulators.
// ---------------------------------------------------------------------------
__global__ __launch_bounds__(256) void k_post(float* __restrict__ rl,
                                              float* __restrict__ rowsum_cur,
                                              float* __restrict__ ss2,
                                              float* __restrict__ t1acc) {
    int idx = blockIdx.x * 256 + threadIdx.x;
    float a = rl[idx] / (rowsum_cur[idx] + 1e-9f);
    rl[idx] = fmaxf(rl[idx] - a * t1acc[idx], 0.0f);
    rowsum_cur[idx] = 0.0f;
    ss2[idx] = 0.0f;
    t1acc[idx] = 0.0f;
}

extern "C" void kernel_launch(void* const* d_in, const int* in_sizes, int n_in,
                              void* d_out, int out_size, void* d_ws, size_t ws_size,
                              hipStream_t stream) {
    const float* xyz1 = (const float*)d_in[0];
    const float* xyz2 = (const float*)d_in[1];
    float* cost = (float*)d_out;

    float* ws = (float*)d_ws;
    float* rl = ws + 0 * BN;
    float* rr[2] = {ws + 1 * BN, ws + 2 * BN};
    float* rs[2] = {ws + 3 * BN, ws + 4 * BN};
    float* ss2 = ws + 5 * BN;
    float* t1acc = ws + 6 * BN;

    static const float levels[10] = {-16384.0f, -4096.0f, -1024.0f, -256.0f,
                                     -64.0f,    -16.0f,   -4.0f,    -1.0f,
                                     -0.25f,    0.0f};
    float c2[10];
    for (int l = 0; l < 10; ++l) c2[l] = levels[l] * LOG2E;

    dim3 grid(NCH, N / RBLK, B);  // 16 x 8 x 16 = 2048 WGs
    dim3 blk(TPB);
    dim3 small(BN / 256);
    dim3 blk256(256);

    k_init<<<small, blk256, 0, stream>>>(rl, rr[0], rs[0], rs[1], ss2, t1acc, cost);
    k_rowsum0<<<grid, blk, 0, stream>>>(xyz1, xyz2, rs[0], c2[0]);

    for (int l = 0; l < 10; ++l) {
        int p = l & 1;
        if (l == 9)
            k_colsum<true><<<grid, blk, 0, stream>>>(xyz1, xyz2, rl, rs[p], rr[p], ss2,
                                                     c2[l]);
        else
            k_colsum<false><<<grid, blk, 0, stream>>>(xyz1, xyz2, rl, rs[p], rr[p], ss2,
                                                      c2[l]);
        if (l <= 7)
            k_fused<0><<<grid, blk, 0, stream>>>(xyz1, xyz2, rr[p], rr[1 - p], ss2, rl,
                                                 rs[p], rs[1 - p], t1acc, cost,
                                                 c2[l], c2[l + 1]);
        else if (l == 8)
            k_fused<1><<<grid, blk, 0, stream>>>(xyz1, xyz2, rr[p], rr[1 - p], ss2, rl,
                                                 rs[p], rs[1 - p], t1acc, cost,
                                                 c2[l], 0.0f);
        else
            k_fused<2><<<grid, blk, 0, stream>>>(xyz1, xyz2, rr[p], rr[1 - p], ss2, rl,
                                                 rs[p], rs[1 - p], t1acc, cost,
                                                 c2[l], 0.0f);
        if (l < 9)
            k_post<<<small, blk256, 0, stream>>>(rl, rs[p], ss2, t1acc);
    }
}